// Round 1
// 2558.601 us; speedup vs baseline: 5.8182x; 5.8182x over previous
//
#include <hip/hip_runtime.h>

// MDLSTM 4-direction wavefront scan, MI355X persistent pipelined kernel.
// B=32, CIN=64, H=32, W=128, OC=128, gates=5*OC=640.
// WG = (dir, column-pair), 256 WGs x 512 threads, flag-pipelined left->right.
// Round N change: all inter-WG comm via RELAXED agent-scope atomics (sc1,
// write-through, no buffer_inv/buffer_wbl2 cache-wide ops), h+c packed in 8B,
// flag published before epilogue, col0 GEMM partially precomputed under the
// poll wait, output stores paired (8B) + nontemporal.

typedef unsigned short ushort_t;
typedef unsigned long long ull_t;
typedef __attribute__((ext_vector_type(8))) short short8;    // 8 bf16 = 16B (MFMA frag)
typedef __attribute__((ext_vector_type(4))) short shortx4;   // 8B
typedef __attribute__((ext_vector_type(4))) float floatx4;
typedef __attribute__((ext_vector_type(2))) float floatx2;

__device__ __forceinline__ float bf2f(ushort_t u) {
    union { unsigned int i; float f; } v; v.i = ((unsigned int)u) << 16; return v.f;
}
__device__ __forceinline__ ushort_t f2bf(float f) {
    union { float f; unsigned int i; } v; v.f = f;
    unsigned int u = v.i;
    u += 0x7fffu + ((u >> 16) & 1u);           // round-to-nearest-even
    return (ushort_t)(u >> 16);
}
__device__ __forceinline__ float frcp(float x) { return __builtin_amdgcn_rcpf(x); }
__device__ __forceinline__ float fsig(float x) { return frcp(1.f + __expf(-x)); }
__device__ __forceinline__ float ftanh(float x) { float e = __expf(2.f * x); return 1.f - 2.f * frcp(e + 1.f); }

// ---------------- init: zero prod/cons counters + flag (1024 u32 = 4KB) ----------------
__global__ void k_init(unsigned int* prod) { prod[threadIdx.x] = 0u; }

// ---------------- dtype sniff: even ushorts of f32 data are mantissa garbage ----------
__global__ void k_sniff(const ushort_t* x, unsigned int* flag) {
    int i = threadIdx.x;                 // 64 lanes
    ushort_t u = x[2 * i];
    int e = (u >> 7) & 0xFF;
    bool plausible = (e >= 118 && e <= 130);   // |val| in ~[2^-9, 8]: true for bf16 N(0,1)
    unsigned long long m = __ballot(plausible);
    if (i == 0) flag[0] = (__popcll(m) >= 32) ? 1u : 0u;   // 1 = bf16, 0 = f32
}

// ---------------- pack weights into MFMA B-frag layouts ----------------
// Wcat rows: k<128 -> u0[k], 128..255 -> u1[k-128], 256..319 -> w0[k-256].
// B-frag (16x16x32): B[k=8*(lane>>4)+j][n=lane&15].
__global__ void k_packw(const void* u0v, const void* u1v, const void* w0v,
                        ushort_t* wcatf, ushort_t* w0f, const unsigned int* flag) {
    const bool isbf = (*flag != 0);
    int id = blockIdx.x * 256 + threadIdx.x;
    if (id >= 4 * 320 * 640) return;
    int d = id / (320 * 640);
    int rem = id % (320 * 640);
    int k = rem / 640, n = rem % 640;
    size_t idx; const void* src;
    if (k < 128)      { src = u0v; idx = (size_t)(d * 128 + k) * 640 + n; }
    else if (k < 256) { src = u1v; idx = (size_t)(d * 128 + (k - 128)) * 640 + n; }
    else              { src = w0v; idx = (size_t)(d * 64 + (k - 256)) * 640 + n; }
    ushort_t v = isbf ? ((const ushort_t*)src)[idx] : f2bf(((const float*)src)[idx]);
    int c = n & 15, ntg = n >> 4, wv = ntg & 7, nt = ntg >> 3;
    int q = (k >> 3) & 3, j = k & 7, ks = k >> 5;
    int lane = c + 16 * q;
    if (ks < 8) wcatf[((((d * 8 + wv) * 8 + ks) * 5 + nt) * 64 + lane) * 8 + j] = v;
    else        w0f[(((d * 2 + (ks - 8)) * 40 + ntg) * 64 + lane) * 8 + j] = v;
}

// ---------------- transpose x (B,CIN,H,W) -> xT[h][w][b][cin] (bf16) ----------------
__global__ void k_packx(const void* xv, ushort_t* xT, const unsigned int* flag) {
    const bool isbf = (*flag != 0);
    __shared__ ushort_t tile[16 * 2048];
    int h = (int)blockIdx.x >> 3, wb = (int)blockIdx.x & 7;
    int w0c = wb * 16;
    int t = threadIdx.x;
    for (int pass = 0; pass < 4; ++pass) {
        int bc = pass * 512 + t;  // bc = b*64 + cin
        size_t base = (size_t)bc * 4096 + h * 128 + w0c;
        if (isbf) {
            const ushort_t* src = (const ushort_t*)xv + base;
            #pragma unroll
            for (int i = 0; i < 16; ++i) tile[i * 2048 + bc] = src[i];
        } else {
            const float* src = (const float*)xv + base;
            #pragma unroll
            for (int i = 0; i < 16; ++i) tile[i * 2048 + bc] = f2bf(src[i]);
        }
    }
    __syncthreads();
    for (int i = 0; i < 16; ++i) {
        ushort_t* dst = xT + (size_t)(h * 128 + w0c + i) * 2048;
        int t4 = t * 4;
        #pragma unroll
        for (int rr = 0; rr < 4; ++rr) dst[t4 + rr] = tile[i * 2048 + t4 + rr];
    }
}

// ---------------- persistent wavefront scan ----------------
// LDS (ushort units):
//   w0lds  : [0, 40960)        w0 B-frags (80 KB)
//   hbuf0  : [40960, 45312)    h(prev) col0, [b][136] padded bf16
//   hbuf1  : [45312, 49664)    h(prev) col1
//   lfbuf  : [49664, 54016)    h from left neighbor (bf16)
//   cbuf_f : [54016, 62464)    c from left neighbor (f32, [b][132] padded)
//   xbuf   : [62464, 67072)    x cell tiles, 2 cols x [b][72] padded bf16
#define LDS_USHORTS 67072

__global__ __launch_bounds__(512, 2) void k_scan(
    const ushort_t* __restrict__ xT, const ushort_t* __restrict__ wcatf,
    const ushort_t* __restrict__ w0f, const void* __restrict__ biasv,
    void* __restrict__ outv, ull_t* __restrict__ comm,
    unsigned int* prod, int ring, const unsigned int* flag) {
    extern __shared__ ushort_t lds[];
    ushort_t* w0lds = lds;
    ushort_t* hbuf0 = lds + 40960;
    ushort_t* hbuf1 = lds + 45312;
    ushort_t* lfbuf = lds + 49664;
    float*    cbuf_f = (float*)(lds + 54016);
    ushort_t* xbuf  = lds + 62464;

    const bool isbf = (*flag != 0);
    const int tid = threadIdx.x;
    const int bx = blockIdx.x;
    const int d = bx >> 6, p = bx & 63;
    const int lane = tid & 63, wv = tid >> 6;
    const int q = lane >> 4, cl = lane & 15;

    // --- load u0/u1 B-frags into registers ---
    short8 bU[8][5];
    {
        const ushort_t* wsrc = wcatf + (size_t)(d * 8 + wv) * 8 * 5 * 512;
        #pragma unroll
        for (int ks = 0; ks < 8; ++ks)
            #pragma unroll
            for (int nt = 0; nt < 5; ++nt)
                bU[ks][nt] = *(const short8*)(wsrc + (ks * 5 + nt) * 512 + lane * 8);
    }
    // --- w0 frags -> LDS (80 KB) ---
    {
        const ushort_t* src = w0f + (size_t)d * 40960;
        for (int i = tid; i < 5120; i += 512)
            *(short8*)(w0lds + i * 8) = *(const short8*)(src + i * 8);
    }
    // --- zero h/lf/c/x buffers (boundary values: h=c=0 at y==0 / x==0) ---
    for (int i = 40960 + tid; i < LDS_USHORTS; i += 512) lds[i] = 0;

    float bias_f[5];
    #pragma unroll
    for (int nt = 0; nt < 5; ++nt) {
        int bi = d * 640 + 16 * (wv + 8 * nt) + cl;
        bias_f[nt] = isbf ? bf2f(((const ushort_t*)biasv)[bi]) : ((const float*)biasv)[bi];
    }

    float cst[2][2][4];  // c-state per lane: [col][mtile][reg], b = 16*mt+4*q+r, oc = 16*wv+cl
    #pragma unroll
    for (int a = 0; a < 2; ++a)
        #pragma unroll
        for (int m = 0; m < 2; ++m)
            #pragma unroll
            for (int r = 0; r < 4; ++r) cst[a][m][r] = 0.f;

    __syncthreads();

    unsigned int* myprod = prod + d * 64 + p;
    unsigned int* lprod  = prod + d * 64 + p - 1;
    unsigned int* cons   = prod + 256;
    unsigned int* mycons = cons + d * 64 + p;
    unsigned int* rcons  = cons + d * 64 + p + 1;
    const int oc = 16 * wv + cl;
    const int xb = tid >> 4, x16 = tid & 15;

    for (int y = 0; y < 32; ++y) {
        // ---- stage x tiles for BOTH columns (hidden under the poll wait) ----
        {
            int fy = (d & 2) ? (31 - y) : y;
            #pragma unroll
            for (int cc = 0; cc < 2; ++cc) {
                int col = 2 * p + cc;
                int fx = (d & 1) ? (127 - col) : col;
                const ushort_t* sx = xT + (size_t)(fy * 128 + fx) * 2048;
                *(shortx4*)(xbuf + cc * 2304 + xb * 72 + x16 * 4) =
                    *(const shortx4*)(sx + xb * 64 + x16 * 4);
            }
        }
        __syncthreads();   // [S1] xbuf visible

        // ---- pre-GEMM col0: bias + h_up part (hbuf0, ks0-3) + x part (ks8-9) ----
        floatx4 acc[2][5];
        #pragma unroll
        for (int mt = 0; mt < 2; ++mt)
            #pragma unroll
            for (int nt = 0; nt < 5; ++nt) {
                floatx4 v = {bias_f[nt], bias_f[nt], bias_f[nt], bias_f[nt]};
                acc[mt][nt] = v;
            }
        #pragma unroll
        for (int ks = 0; ks < 4; ++ks) {
            short8 a0 = *(const short8*)(hbuf0 + cl * 136 + 32 * ks + 8 * q);
            short8 a1 = *(const short8*)(hbuf0 + (cl + 16) * 136 + 32 * ks + 8 * q);
            #pragma unroll
            for (int nt = 0; nt < 5; ++nt) {
                acc[0][nt] = __builtin_amdgcn_mfma_f32_16x16x32_bf16(a0, bU[ks][nt], acc[0][nt], 0, 0, 0);
                acc[1][nt] = __builtin_amdgcn_mfma_f32_16x16x32_bf16(a1, bU[ks][nt], acc[1][nt], 0, 0, 0);
            }
        }
        #pragma unroll
        for (int ks = 0; ks < 2; ++ks) {
            short8 a0 = *(const short8*)(xbuf + cl * 72 + 32 * ks + 8 * q);
            short8 a1 = *(const short8*)(xbuf + (cl + 16) * 72 + 32 * ks + 8 * q);
            #pragma unroll
            for (int nt = 0; nt < 5; ++nt) {
                short8 bf = *(const short8*)(w0lds + ((ks * 40 + (wv + 8 * nt)) * 64 + lane) * 8);
                acc[0][nt] = __builtin_amdgcn_mfma_f32_16x16x32_bf16(a0, bf, acc[0][nt], 0, 0, 0);
                acc[1][nt] = __builtin_amdgcn_mfma_f32_16x16x32_bf16(a1, bf, acc[1][nt], 0, 0, 0);
            }
        }

        // ---- acquire left-neighbor (h,c) for row y: relaxed poll, no buffer_inv ----
        if (p > 0 && tid == 0) {
            int it = 0;
            while (__hip_atomic_load(lprod, __ATOMIC_RELAXED, __HIP_MEMORY_SCOPE_AGENT) < (unsigned)(y + 1)) {
                __builtin_amdgcn_s_sleep(1);
                if (++it > 10000000) break;  // safety: never hang forever
            }
        }
        __syncthreads();   // [S2] flag observed by all
        if (p > 0) {
            // sc1 loads go to the agent coherence point -> always fresh, no fence needed
            size_t slot = ((size_t)(d * 64 + (p - 1)) * ring + (size_t)(y & (ring - 1))) * 4096;
            const ull_t* src = comm + slot + (size_t)xb * 128 + x16 * 8;
            #pragma unroll
            for (int r = 0; r < 8; ++r) {
                ull_t v = __hip_atomic_load((ull_t*)(src + r), __ATOMIC_RELAXED, __HIP_MEMORY_SCOPE_AGENT);
                union { unsigned int u; float f; } cv; cv.u = (unsigned int)v;
                cbuf_f[xb * 132 + x16 * 8 + r] = cv.f;
                lfbuf[xb * 136 + x16 * 8 + r] = (ushort_t)(v >> 32);
            }
        }
        __syncthreads();   // [S3] lf/c staged in LDS
        if (p > 0 && tid == 0)
            __hip_atomic_store(mycons, (unsigned)(y + 1), __ATOMIC_RELAXED, __HIP_MEMORY_SCOPE_AGENT);

        // ---- finish col0: h_lf part (ks4-7) ----
        #pragma unroll
        for (int ks = 4; ks < 8; ++ks) {
            short8 a0 = *(const short8*)(lfbuf + cl * 136 + 32 * (ks - 4) + 8 * q);
            short8 a1 = *(const short8*)(lfbuf + (cl + 16) * 136 + 32 * (ks - 4) + 8 * q);
            #pragma unroll
            for (int nt = 0; nt < 5; ++nt) {
                acc[0][nt] = __builtin_amdgcn_mfma_f32_16x16x32_bf16(a0, bU[ks][nt], acc[0][nt], 0, 0, 0);
                acc[1][nt] = __builtin_amdgcn_mfma_f32_16x16x32_bf16(a1, bU[ks][nt], acc[1][nt], 0, 0, 0);
            }
        }
        // ---- elementwise col0 ----
        float hN0[2][4];
        #pragma unroll
        for (int mt = 0; mt < 2; ++mt)
            #pragma unroll
            for (int r = 0; r < 4; ++r) {
                float ii = fsig(acc[mt][0][r]);
                float ff = fsig(acc[mt][1][r]);
                float gg = ftanh(acc[mt][2][r]);
                float oo = fsig(acc[mt][3][r]);
                float ll = fsig(acc[mt][4][r]);
                int b = 16 * mt + 4 * q + r;
                float cup = cst[0][mt][r];
                float clf = cbuf_f[b * 132 + oc];
                float cn = ff * (ll * cup + (1.f - ll) * clf) + ii * gg;
                cst[0][mt][r] = cn;
                hN0[mt][r] = oo * ftanh(cn);
            }
        // write h0 to own LDS ring (hbuf0 reads all completed before S2)
        #pragma unroll
        for (int mt = 0; mt < 2; ++mt)
            #pragma unroll
            for (int r = 0; r < 4; ++r)
                hbuf0[(16 * mt + 4 * q + r) * 136 + oc] = f2bf(hN0[mt][r]);
        __syncthreads();   // [D0] h0 visible for col1 GEMM

        // ---- col1 full GEMM: ks0-3 hbuf1(prev row), ks4-7 hbuf0(col0 now), ks8-9 x ----
        #pragma unroll
        for (int mt = 0; mt < 2; ++mt)
            #pragma unroll
            for (int nt = 0; nt < 5; ++nt) {
                floatx4 v = {bias_f[nt], bias_f[nt], bias_f[nt], bias_f[nt]};
                acc[mt][nt] = v;
            }
        #pragma unroll
        for (int ks = 0; ks < 10; ++ks) {
            short8 a0, a1;
            if (ks < 4) {
                a0 = *(const short8*)(hbuf1 + cl * 136 + 32 * ks + 8 * q);
                a1 = *(const short8*)(hbuf1 + (cl + 16) * 136 + 32 * ks + 8 * q);
            } else if (ks < 8) {
                a0 = *(const short8*)(hbuf0 + cl * 136 + 32 * (ks - 4) + 8 * q);
                a1 = *(const short8*)(hbuf0 + (cl + 16) * 136 + 32 * (ks - 4) + 8 * q);
            } else {
                a0 = *(const short8*)(xbuf + 2304 + cl * 72 + 32 * (ks - 8) + 8 * q);
                a1 = *(const short8*)(xbuf + 2304 + (cl + 16) * 72 + 32 * (ks - 8) + 8 * q);
            }
            #pragma unroll
            for (int nt = 0; nt < 5; ++nt) {
                short8 bf = (ks < 8) ? bU[ks][nt]
                    : *(const short8*)(w0lds + (((ks - 8) * 40 + (wv + 8 * nt)) * 64 + lane) * 8);
                acc[0][nt] = __builtin_amdgcn_mfma_f32_16x16x32_bf16(a0, bf, acc[0][nt], 0, 0, 0);
                acc[1][nt] = __builtin_amdgcn_mfma_f32_16x16x32_bf16(a1, bf, acc[1][nt], 0, 0, 0);
            }
        }
        // ---- elementwise col1 ----
        float hN1[2][4];
        #pragma unroll
        for (int mt = 0; mt < 2; ++mt)
            #pragma unroll
            for (int r = 0; r < 4; ++r) {
                float ii = fsig(acc[mt][0][r]);
                float ff = fsig(acc[mt][1][r]);
                float gg = ftanh(acc[mt][2][r]);
                float oo = fsig(acc[mt][3][r]);
                float ll = fsig(acc[mt][4][r]);
                float cup = cst[1][mt][r];
                float clf = cst[0][mt][r];
                float cn = ff * (ll * cup + (1.f - ll) * clf) + ii * gg;
                cst[1][mt][r] = cn;
                hN1[mt][r] = oo * ftanh(cn);
            }
        // back-pressure (only if ring < rows): slot y&(ring-1) must be consumed
        if (p < 63 && y >= ring && tid == 0) {
            int it = 0;
            while ((int)__hip_atomic_load(rcons, __ATOMIC_RELAXED, __HIP_MEMORY_SCOPE_AGENT) < y - ring + 1) {
                __builtin_amdgcn_s_sleep(1);
                if (++it > 10000000) break;
            }
        }
        __syncthreads();   // [B1] col1 LDS reads done + back-pressure honored

        // ---- publish (h,c) packed 8B via relaxed sc1 stores, then flag ----
        if (p < 63) {
            size_t slot = ((size_t)(d * 64 + p) * ring + (size_t)(y & (ring - 1))) * 4096;
            #pragma unroll
            for (int mt = 0; mt < 2; ++mt)
                #pragma unroll
                for (int r = 0; r < 4; ++r) {
                    int b = 16 * mt + 4 * q + r;
                    union { float f; unsigned int u; } cv; cv.f = cst[1][mt][r];
                    ull_t v = (ull_t)cv.u | ((ull_t)(unsigned int)f2bf(hN1[mt][r]) << 32);
                    __hip_atomic_store(comm + slot + (size_t)b * 128 + oc, v,
                                       __ATOMIC_RELAXED, __HIP_MEMORY_SCOPE_AGENT);
                }
            asm volatile("s_waitcnt vmcnt(0)" ::: "memory");  // data at coherence point
            __syncthreads();   // [C1] all waves' data acked before flag
            if (tid == 0)
                __hip_atomic_store(myprod, (unsigned)(y + 1), __ATOMIC_RELAXED, __HIP_MEMORY_SCOPE_AGENT);
        }

        // ---- epilogue (off the handoff critical path): h1 to LDS + paired outputs ----
        #pragma unroll
        for (int mt = 0; mt < 2; ++mt)
            #pragma unroll
            for (int r = 0; r < 4; ++r) {
                int b = 16 * mt + 4 * q + r;
                hbuf1[b * 136 + oc] = f2bf(hN1[mt][r]);
                size_t oi = ((size_t)((b * 4 + d) * 128 + oc) * 32 + y) * 128 + 2 * p;
                if (isbf) {
                    unsigned int pk = (unsigned int)f2bf(hN0[mt][r]) |
                                      ((unsigned int)f2bf(hN1[mt][r]) << 16);
                    __builtin_nontemporal_store(pk, (unsigned int*)((ushort_t*)outv + oi));
                } else {
                    floatx2 v2 = {hN0[mt][r], hN1[mt][r]};
                    __builtin_nontemporal_store(v2, (floatx2*)((float*)outv + oi));
                }
            }
        // no end-of-row barrier needed: all LDS reads of xbuf/hbuf1/lfbuf completed by B1,
        // and next row's writes to lfbuf/cbuf/hbuf0 sit behind S2'/S3' collective barriers.
    }
}

extern "C" void kernel_launch(void* const* d_in, const int* in_sizes, int n_in,
                              void* d_out, int out_size, void* d_ws, size_t ws_size,
                              hipStream_t stream) {
    const void* x  = d_in[0];   // (32,64,32,128)
    const void* w0 = d_in[1];   // (4,64,640)
    const void* u0 = d_in[2];   // (4,128,640)
    const void* u1 = d_in[3];   // (4,128,640)
    const void* bs = d_in[4];   // (4,640)

    // ---- workspace layout ----
    const size_t CTRLB  = 4096;                          // prod(256) cons(256) flag pad
    const size_t WCATB  = 4ull * 8 * 8 * 5 * 512 * 2;    // 1,310,720
    const size_t W0FB   = 4ull * 2 * 40 * 64 * 8 * 2;    //   327,680
    const size_t XTB    = 32ull * 128 * 32 * 64 * 2;     // 16,777,216
    const size_t fixed  = CTRLB + WCATB + W0FB + XTB;    // ~17.6 MB
    int ring = 32;
    // comm bytes per ring-row: 256 producers * 4096 packed 8B = 8 MiB
    while (ring > 2 && fixed + (size_t)ring * 8388608ull > ws_size) ring >>= 1;

    char* w = (char*)d_ws;
    unsigned int* prod = (unsigned int*)w;
    unsigned int* flag = prod + 512;
    ushort_t* wcatf = (ushort_t*)(w + CTRLB);
    ushort_t* w0f   = (ushort_t*)(w + CTRLB + WCATB);
    ushort_t* xT    = (ushort_t*)(w + CTRLB + WCATB + W0FB);
    ull_t*    comm  = (ull_t*)(w + fixed);

    (void)hipFuncSetAttribute((const void*)k_scan,
                              hipFuncAttributeMaxDynamicSharedMemorySize,
                              LDS_USHORTS * 2);

    hipLaunchKernelGGL(k_init, dim3(1), dim3(1024), 0, stream, prod);
    hipLaunchKernelGGL(k_sniff, dim3(1), dim3(64), 0, stream, (const ushort_t*)x, flag);
    hipLaunchKernelGGL(k_packw, dim3(3200), dim3(256), 0, stream, u0, u1, w0, wcatf, w0f, flag);
    hipLaunchKernelGGL(k_packx, dim3(256), dim3(512), 0, stream, x, xT, flag);
    hipLaunchKernelGGL(k_scan, dim3(256), dim3(512), LDS_USHORTS * 2, stream,
                       xT, wcatf, w0f, bs, d_out, comm, prod, ring, flag);
}